// Round 10
// baseline (1849.842 us; speedup 1.0000x reference)
//
#include <hip/hip_runtime.h>
#include <hip/hip_bf16.h>

// All tensors fp32. Output = [y (2048) | hT (2*1024*32)] fp32.
#define NPER 128

// branchless stable top-4 insert, strict < (earlier candidate wins ties)
__device__ __forceinline__ void ins4(float d, int id, float* bd, int* bi) {
    const bool c0 = d < bd[0], c1 = d < bd[1], c2 = d < bd[2], c3 = d < bd[3];
    bd[3] = c2 ? bd[2] : (c3 ? d : bd[3]);  bi[3] = c2 ? bi[2] : (c3 ? id : bi[3]);
    bd[2] = c1 ? bd[1] : (c2 ? d : bd[2]);  bi[2] = c1 ? bi[1] : (c2 ? id : bi[2]);
    bd[1] = c0 ? bd[0] : (c1 ? d : bd[1]);  bi[1] = c0 ? bi[0] : (c1 ? id : bi[1]);
    bd[0] = c0 ? d : bd[0];                 bi[0] = c0 ? id : bi[0];
}

// ---------------------------------------------------------------------------
// k_prep (R4-verified): W2I[32][64][4]; nn2WT[64][94]; WfT[96][256]
// ---------------------------------------------------------------------------
__global__ void k_prep(const float* __restrict__ W2,
                       const float* __restrict__ nn2W,
                       const float* __restrict__ nn1W,
                       float* __restrict__ W2I, float* __restrict__ nn2WT,
                       float* __restrict__ WfT)
{
    int i = blockIdx.x * 256 + threadIdx.x;
    if (i < 8192) {                       // W2I
        int ch4 = i >> 8, rem = i & 255, c = rem >> 2, sub = rem & 3;
        W2I[i] = W2[c * 128 + (ch4 * 4 + sub)];
    } else if (i < 8192 + 6016) {         // nn2WT
        int j = i - 8192, ch = j / 94, c = j - ch * 94;
        nn2WT[j] = nn2W[c * 64 + ch];
    } else if (i < 8192 + 6016 + 24576) { // WfT (96 rows x 256)
        int k = i - 14208, jj = k >> 8, r = k & 255;
        float v = 0.0f;
        if (jj < 94) {
            if (r < 128) v = nn1W[r * 94 + jj];
            else {
                int c = r - 128;
                v = 0.25f * nn1W[(128 + c) * 94 + jj] + nn1W[(256 + c) * 94 + jj];
            }
        }
        WfT[k] = v;
    }
}

// ---------------------------------------------------------------------------
// k_edge: block = (graph, half of 64 nodes), 256 threads = 4 waves.
// R9 math (bitwise-identical); 40 KB LDS pool -> 4 blocks/CU.
// amdgpu_waves_per_eu(4,4): pin exactly 4 waves/EU so the allocator uses the
// full 128-VGPR budget instead of spilling to chase 6+ waves (R8/R9 failure:
// VGPR 64-76 + 300-700 MB scratch traffic).
// ---------------------------------------------------------------------------
__global__ __launch_bounds__(256)
__attribute__((amdgpu_waves_per_eu(4, 4)))
void k_edge(
    const float* __restrict__ x,      // [N,5]
    const float* __restrict__ W1,     // [10,64]
    const float* __restrict__ b1,     // [64]
    const float* __restrict__ W2I,    // [32][64][4]
    const float* __restrict__ b2,     // [128]
    const float* __restrict__ WfT,    // [96,256]
    const float* __restrict__ nn1b,   // [94]
    const float* __restrict__ nn2WT,  // [64,94]
    const float* __restrict__ nn2b,   // [64]
    float* __restrict__ pmax,         // [4096,64]
    float* __restrict__ pmin,
    float* __restrict__ psum)
{
    __shared__ float pool[10240];     // 40960 B -> 4 blocks/CU
    float* XS  = pool;                      // [640]   phase 1
    float* KD  = pool + 640;                // [1024]  phase 1
    int*   KI  = (int*)(pool + 1664);       // [1024]  phase 1
    int*   NBR = (int*)(pool + 2688);       // [256]   phase 1
    float* AGM = pool;                      // [4352]  phase 2 (64x68)
    float* AGS = pool + 4352;               // [4352]  phase 2
    float* NNH = pool;                      // [6016]  phase 3 (94x64 ch-major)
    float* HT  = pool + 6016;               // [4224]  phase 3 (64x66)

    const int t = threadIdx.x;
    const int lane = t & 63;
    // wave id in an SGPR so weight addresses are provably wave-uniform (s_load)
    const int w = __builtin_amdgcn_readfirstlane(t >> 6);
    const int graph = blockIdx.x >> 1;
    const int node0 = (blockIdx.x & 1) * 64;

    for (int i = t; i < NPER * 5; i += 256) XS[i] = x[(size_t)graph * (NPER * 5) + i];
    __syncthreads();

    // ---- KNN: 4 threads per node (q = t>>6), branchless insert, LDS merge
    {
        const int nl2 = t & 63;
        const int q  = t >> 6;
        const int ng2 = node0 + nl2;
        const float px = XS[ng2 * 5 + 0], py = XS[ng2 * 5 + 1], pz = XS[ng2 * 5 + 2];
        float bd[4] = {3e38f, 3e38f, 3e38f, 3e38f};
        int   bi[4] = {0, 0, 0, 0};
        const int m0 = q * 32;
        for (int m = m0; m < m0 + 32; ++m) {
            float dx = XS[m * 5 + 0] - px, dy = XS[m * 5 + 1] - py, dz = XS[m * 5 + 2] - pz;
            float d2 = __fadd_rn(__fadd_rn(__fmul_rn(dx, dx), __fmul_rn(dy, dy)),
                                 __fmul_rn(dz, dz));
            d2 = (m == ng2) ? 3.0e38f : d2;   // self never inserted (strict <)
            ins4(d2, m, bd, bi);
        }
        #pragma unroll
        for (int s = 0; s < 4; ++s) { KD[(q * 4 + s) * 64 + nl2] = bd[s]; KI[(q * 4 + s) * 64 + nl2] = bi[s]; }
    }
    __syncthreads();
    if (t < 64) {                           // merge quarters in global index order
        float bd[4] = {3e38f, 3e38f, 3e38f, 3e38f};
        int   bi[4] = {0, 0, 0, 0};
        #pragma unroll
        for (int q = 0; q < 4; ++q)
            #pragma unroll
            for (int s = 0; s < 4; ++s)
                ins4(KD[(q * 4 + s) * 64 + t], KI[(q * 4 + s) * 64 + t], bd, bi);
        #pragma unroll
        for (int s = 0; s < 4; ++s) NBR[t * 4 + s] = bi[s];
    }
    __syncthreads();

    // ---- MLP1: lane-per-edge, h1[64] in registers (W1/b1 uniform -> s_load)
    const int nl = t >> 2;
    const int kk = t & 3;
    const int n_g = node0 + nl;
    const int j   = NBR[nl * 4 + kk];
    float f[10];
    #pragma unroll
    for (int d = 0; d < 5; ++d) { f[d] = XS[n_g * 5 + d]; f[5 + d] = XS[j * 5 + d] - f[d]; }
    float h1v[64];
    #pragma unroll
    for (int c = 0; c < 64; ++c) h1v[c] = b1[c];
    #pragma unroll
    for (int d = 0; d < 10; ++d) {
        float fd = f[d];
        #pragma unroll
        for (int c = 0; c < 64; ++c) h1v[c] = fmaf(fd, W1[d * 64 + c], h1v[c]);
    }
    #pragma unroll
    for (int c = 0; c < 64; ++c) h1v[c] = fmaxf(h1v[c], 0.0f);
    __syncthreads();   // XS/NBR dead; AGM/AGS may alias them now

    // ---- nn1 accumulators (wave owns 24 jj channels, node = lane)
    float acc[24];
    const int jj0 = __builtin_amdgcn_readfirstlane(w * 24);
    #pragma unroll
    for (int i = 0; i < 24; ++i) acc[i] = (jj0 + i < 94) ? nn1b[jj0 + i] : 0.0f;

    for (int h = 0; h < 2; ++h) {
        // MLP2: 16 groups of 4 channels -> 4 independent FMA chains
        for (int ch = 0; ch < 64; ch += 4) {
            const float* wp = W2I + (size_t)(h * 16 + (ch >> 2)) * 256;  // uniform
            float m0 = b2[h * 64 + ch], m1 = b2[h * 64 + ch + 1];
            float m2 = b2[h * 64 + ch + 2], m3 = b2[h * 64 + ch + 3];
            #pragma unroll
            for (int c = 0; c < 64; ++c) {
                float hv = h1v[c];
                m0 = fmaf(hv, wp[c * 4 + 0], m0);
                m1 = fmaf(hv, wp[c * 4 + 1], m1);
                m2 = fmaf(hv, wp[c * 4 + 2], m2);
                m3 = fmaf(hv, wp[c * 4 + 3], m3);
            }
            m0 = fmaxf(m0, 0.0f); m1 = fmaxf(m1, 0.0f);
            m2 = fmaxf(m2, 0.0f); m3 = fmaxf(m3, 0.0f);
            float x0 = fmaxf(m0, __shfl_xor(m0, 1));
            float x1 = fmaxf(m1, __shfl_xor(m1, 1));
            float x2 = fmaxf(m2, __shfl_xor(m2, 1));
            float x3 = fmaxf(m3, __shfl_xor(m3, 1));
            x0 = fmaxf(x0, __shfl_xor(x0, 2));
            x1 = fmaxf(x1, __shfl_xor(x1, 2));
            x2 = fmaxf(x2, __shfl_xor(x2, 2));
            x3 = fmaxf(x3, __shfl_xor(x3, 2));
            float s0 = m0 + __shfl_xor(m0, 1);
            float s1 = m1 + __shfl_xor(m1, 1);
            float s2 = m2 + __shfl_xor(m2, 1);
            float s3 = m3 + __shfl_xor(m3, 1);
            s0 += __shfl_xor(s0, 2);
            s1 += __shfl_xor(s1, 2);
            s2 += __shfl_xor(s2, 2);
            s3 += __shfl_xor(s3, 2);
            if (kk == 0) {
                *(float4*)&AGM[nl * 68 + ch] = make_float4(x0, x1, x2, x3);
                *(float4*)&AGS[nl * 68 + ch] = make_float4(s0, s1, s2, s3);
            }
        }
        __syncthreads();

        // nn1 partial: lane = node; agg rows via b128 (chunks of 8 to keep
        // peak VGPR <= 128); same c-accumulation order -> bitwise identical
        for (int cb = 0; cb < 64; cb += 8) {
            float am[8], as_[8];
            #pragma unroll
            for (int i = 0; i < 2; ++i) {
                *(float4*)&am[i * 4]  = *(const float4*)&AGM[lane * 68 + cb + i * 4];
                *(float4*)&as_[i * 4] = *(const float4*)&AGS[lane * 68 + cb + i * 4];
            }
            #pragma unroll 2
            for (int i2 = 0; i2 < 24; ++i2) {
                const float* wa = WfT + (size_t)(jj0 + i2) * 256 + h * 64 + cb;
                const float* wb = wa + 128;
                float a = acc[i2];
                #pragma unroll
                for (int i = 0; i < 8; ++i) a = fmaf(am[i], wa[i], fmaf(as_[i], wb[i], a));
                acc[i2] = a;
            }
        }
        __syncthreads();   // before next half overwrites agg / NNH alias
    }

    // ---- nnh = relu(nn1), channel-major [jj][node] (conflict-free stride 64)
    #pragma unroll
    for (int i2 = 0; i2 < 24; ++i2)
        if (jj0 + i2 < 94) NNH[(jj0 + i2) * 64 + lane] = fmaxf(acc[i2], 0.0f);
    __syncthreads();

    // ---- nn2: lane = node, wave owns 16 output channels (weights s_load)
    {
        const int ch0 = __builtin_amdgcn_readfirstlane(w * 16);
        float acc2[16];
        #pragma unroll
        for (int i = 0; i < 16; ++i) acc2[i] = nn2b[ch0 + i];
        for (int cb = 0; cb < 94; cb += 32) {
            const int cn = (cb == 64) ? 30 : 32;
            float hv[32];
            for (int i = 0; i < cn; ++i) hv[i] = NNH[(cb + i) * 64 + lane];
            #pragma unroll
            for (int i = 0; i < 16; ++i) {
                const float* wp = nn2WT + (size_t)(ch0 + i) * 94 + cb;
                float a = acc2[i];
                for (int c = 0; c < cn; ++c) a = fmaf(hv[c], wp[c], a);
                acc2[i] = a;
            }
        }
        #pragma unroll
        for (int i = 0; i < 8; ++i)
            *(float2*)&HT[lane * 66 + ch0 + i * 2] =
                make_float2(acc2[i * 2], acc2[i * 2 + 1]);
    }
    __syncthreads();

    // ---- partial pooling over this block's 64 nodes
    if (t < 64) {
        float mx = -3e38f, mn = 3e38f, sm = 0.0f;
        for (int n = 0; n < 64; ++n) {
            float v = HT[n * 66 + t];
            mx = fmaxf(mx, v); mn = fminf(mn, v); sm += v;
        }
        pmax[(size_t)blockIdx.x * 64 + t] = mx;
        pmin[(size_t)blockIdx.x * 64 + t] = mn;
        psum[(size_t)blockIdx.x * 64 + t] = sm;
    }
}

// ---------------------------------------------------------------------------
__global__ void k_pool(const float* __restrict__ pmax, const float* __restrict__ pmin,
                       const float* __restrict__ psum, float* __restrict__ g_out)
{
    const int t = threadIdx.x;
    const int g = blockIdx.x * 4 + (t >> 6);
    const int ch = t & 63;
    const size_t a = (size_t)(2 * g) * 64 + ch, b = a + 64;
    float mx = fmaxf(pmax[a], pmax[b]);
    float mn = fminf(pmin[a], pmin[b]);
    float sm = psum[a] + psum[b];
    float* gp = g_out + (size_t)g * 256;
    gp[ch]        = fmaxf(mx, 0.0f);
    gp[64 + ch]   = fmaxf(mn, 0.0f);
    gp[128 + ch]  = fmaxf(sm, 0.0f);
    gp[192 + ch]  = fmaxf(sm * (1.0f / 128.0f), 0.0f);
}

// ---------------------------------------------------------------------------
__global__ __launch_bounds__(128) void k_gru(
    const float* __restrict__ g, const float* __restrict__ h1_in,
    const float* __restrict__ wih0, const float* __restrict__ whh0,
    const float* __restrict__ bih0, const float* __restrict__ bhh0,
    const float* __restrict__ wih1, const float* __restrict__ whh1,
    const float* __restrict__ bih1, const float* __restrict__ bhh1,
    float* __restrict__ out1, float* __restrict__ hT)
{
    __shared__ float xt[4][256];
    __shared__ float h0[4][32];
    __shared__ float h1l[4][32];
    const int tid = threadIdx.x;
    const int e = tid >> 5;
    const int j = tid & 31;
    const int b = blockIdx.x * 4 + e;

    h0[e][j]  = h1_in[b * 32 + j];
    h1l[e][j] = h1_in[32768 + b * 32 + j];
    __syncthreads();

    for (int t = 0; t < 2; ++t) {
        for (int c = j; c < 256; c += 32)
            xt[e][c] = g[(size_t)(t * 1024 + 4 * c + (b >> 8)) * 256 + (b & 255)];
        __syncthreads();

        float gi0 = bih0[j], gi1 = bih0[32 + j], gi2 = bih0[64 + j];
        for (int c = 0; c < 256; ++c) {
            float xv = xt[e][c];
            gi0 += xv * wih0[j * 256 + c];
            gi1 += xv * wih0[(32 + j) * 256 + c];
            gi2 += xv * wih0[(64 + j) * 256 + c];
        }
        float gh0 = bhh0[j], gh1 = bhh0[32 + j], gh2 = bhh0[64 + j];
        #pragma unroll
        for (int c = 0; c < 32; ++c) {
            float hv = h0[e][c];
            gh0 += hv * whh0[j * 32 + c];
            gh1 += hv * whh0[(32 + j) * 32 + c];
            gh2 += hv * whh0[(64 + j) * 32 + c];
        }
        float r = 1.0f / (1.0f + expf(-(gi0 + gh0)));
        float z = 1.0f / (1.0f + expf(-(gi1 + gh1)));
        float nn = tanhf(gi2 + r * gh2);
        float hn0 = (1.0f - z) * nn + z * h0[e][j];
        __syncthreads();
        h0[e][j] = hn0;
        __syncthreads();

        float ai0 = bih1[j], ai1 = bih1[32 + j], ai2 = bih1[64 + j];
        #pragma unroll
        for (int c = 0; c < 32; ++c) {
            float xv = h0[e][c];
            ai0 += xv * wih1[j * 32 + c];
            ai1 += xv * wih1[(32 + j) * 32 + c];
            ai2 += xv * wih1[(64 + j) * 32 + c];
        }
        float ah0 = bhh1[j], ah1 = bhh1[32 + j], ah2 = bhh1[64 + j];
        #pragma unroll
        for (int c = 0; c < 32; ++c) {
            float hv = h1l[e][c];
            ah0 += hv * whh1[j * 32 + c];
            ah1 += hv * whh1[(32 + j) * 32 + c];
            ah2 += hv * whh1[(64 + j) * 32 + c];
        }
        float r1 = 1.0f / (1.0f + expf(-(ai0 + ah0)));
        float z1 = 1.0f / (1.0f + expf(-(ai1 + ah1)));
        float n1 = tanhf(ai2 + r1 * ah2);
        float hn1 = (1.0f - z1) * n1 + z1 * h1l[e][j];
        __syncthreads();
        h1l[e][j] = hn1;
        out1[(size_t)(t * 1024 + b) * 32 + j] = hn1;
        __syncthreads();
    }
    hT[b * 32 + j]         = h0[e][j];
    hT[32768 + b * 32 + j] = h1l[e][j];
}

__global__ void k_final(const float* __restrict__ out1,
                        const float* __restrict__ nn4W, const float* __restrict__ nn4b,
                        float* __restrict__ y)
{
    const int r = blockIdx.x * 256 + threadIdx.x;
    if (r >= 2048) return;
    const int t = r >> 10, rp = r & 1023;
    const int f = rp >> 5, bb0 = (rp & 31) << 5;
    float acc = nn4b[0];
    #pragma unroll
    for (int c = 0; c < 32; ++c)
        acc += fmaxf(out1[(size_t)(t * 1024 + bb0 + c) * 32 + f], 0.0f) * nn4W[c];
    y[r] = fmaxf(acc, 0.0f);
}

extern "C" void kernel_launch(void* const* d_in, const int* in_sizes, int n_in,
                              void* d_out, int out_size, void* d_ws, size_t ws_size,
                              hipStream_t stream) {
    const float* x    = (const float*)d_in[0];
    const float* h1i  = (const float*)d_in[2];
    const float* W1   = (const float*)d_in[3];
    const float* b1   = (const float*)d_in[4];
    const float* W2   = (const float*)d_in[5];
    const float* b2   = (const float*)d_in[6];
    const float* nn1W = (const float*)d_in[7];
    const float* nn1b = (const float*)d_in[8];
    const float* nn2W = (const float*)d_in[9];
    const float* nn2b = (const float*)d_in[10];
    const float* nn4W = (const float*)d_in[11];
    const float* nn4b = (const float*)d_in[12];
    const float* wih0 = (const float*)d_in[13];
    const float* whh0 = (const float*)d_in[14];
    const float* bih0 = (const float*)d_in[15];
    const float* bhh0 = (const float*)d_in[16];
    const float* wih1 = (const float*)d_in[17];
    const float* whh1 = (const float*)d_in[18];
    const float* bih1 = (const float*)d_in[19];
    const float* bhh1 = (const float*)d_in[20];

    float* ws = (float*)d_ws;
    float* g_buf  = ws;                   // 524288
    float* out1   = g_buf + 524288;       // 65536
    float* W2I    = out1 + 65536;         // 8192
    float* nn2WT  = W2I + 8192;           // 6016
    float* WfT    = nn2WT + 6016;         // 24576 (96x256)
    float* pmax   = WfT + 24576;          // 262144
    float* pmin   = pmax + 262144;        // 262144
    float* psum   = pmin + 262144;        // 262144

    float* y  = (float*)d_out;            // [2048]
    float* hT = y + 2048;                 // [2,1024,32]

    hipLaunchKernelGGL(k_prep, dim3(152), dim3(256), 0, stream,
                       W2, nn2W, nn1W, W2I, nn2WT, WfT);
    hipLaunchKernelGGL(k_edge, dim3(4096), dim3(256), 0, stream,
                       x, W1, b1, W2I, b2, WfT, nn1b, nn2WT, nn2b,
                       pmax, pmin, psum);
    hipLaunchKernelGGL(k_pool, dim3(512), dim3(256), 0, stream,
                       pmax, pmin, psum, g_buf);
    hipLaunchKernelGGL(k_gru, dim3(256), dim3(128), 0, stream,
                       g_buf, h1i, wih0, whh0, bih0, bhh0,
                       wih1, whh1, bih1, bhh1, out1, hT);
    hipLaunchKernelGGL(k_final, dim3(8), dim3(256), 0, stream,
                       out1, nn4W, nn4b, y);
}

// Round 11
// 894.307 us; speedup vs baseline: 2.0685x; 2.0685x over previous
//
#include <hip/hip_runtime.h>
#include <hip/hip_bf16.h>

// All tensors fp32. Output = [y (2048) | hT (2*1024*32)] fp32.
#define NPER 128

// branchless stable top-4 insert, strict < (earlier candidate wins ties)
__device__ __forceinline__ void ins4(float d, int id, float* bd, int* bi) {
    const bool c0 = d < bd[0], c1 = d < bd[1], c2 = d < bd[2], c3 = d < bd[3];
    bd[3] = c2 ? bd[2] : (c3 ? d : bd[3]);  bi[3] = c2 ? bi[2] : (c3 ? id : bi[3]);
    bd[2] = c1 ? bd[1] : (c2 ? d : bd[2]);  bi[2] = c1 ? bi[1] : (c2 ? id : bi[2]);
    bd[1] = c0 ? bd[0] : (c1 ? d : bd[1]);  bi[1] = c0 ? bi[0] : (c1 ? id : bi[1]);
    bd[0] = c0 ? d : bd[0];                 bi[0] = c0 ? id : bi[0];
}

// ---------------------------------------------------------------------------
// k_prep (R4-verified): W2I[32][64][4]; nn2WT[64][94]; WfT[96][256]
// ---------------------------------------------------------------------------
__global__ void k_prep(const float* __restrict__ W2,
                       const float* __restrict__ nn2W,
                       const float* __restrict__ nn1W,
                       float* __restrict__ W2I, float* __restrict__ nn2WT,
                       float* __restrict__ WfT)
{
    int i = blockIdx.x * 256 + threadIdx.x;
    if (i < 8192) {                       // W2I
        int ch4 = i >> 8, rem = i & 255, c = rem >> 2, sub = rem & 3;
        W2I[i] = W2[c * 128 + (ch4 * 4 + sub)];
    } else if (i < 8192 + 6016) {         // nn2WT
        int j = i - 8192, ch = j / 94, c = j - ch * 94;
        nn2WT[j] = nn2W[c * 64 + ch];
    } else if (i < 8192 + 6016 + 24576) { // WfT (96 rows x 256)
        int k = i - 14208, jj = k >> 8, r = k & 255;
        float v = 0.0f;
        if (jj < 94) {
            if (r < 128) v = nn1W[r * 94 + jj];
            else {
                int c = r - 128;
                v = 0.25f * nn1W[(128 + c) * 94 + jj] + nn1W[(256 + c) * 94 + jj];
            }
        }
        WfT[k] = v;
    }
}

// ---------------------------------------------------------------------------
// k_edge: block = (graph, half of 64 nodes), 256 threads = 4 waves.
// R10 math (bitwise-identical); 40 KB LDS pool -> 4 blocks/CU.
// __launch_bounds__(256,2): allocator model from R5/R8/R9/R10 counters —
// VGPR target = (512/min_waves)/2 -> min_waves=2 targets 128 VGPR. 128 VGPR
// still runs 4 waves/EU, so LDS occupancy is preserved and the ~115-reg live
// set fits with NO scratch spill (R9/R10: VGPR 64 + 400-780 MB spill traffic).
// All register arrays are constant-indexed (loops fully unrolled; nn2 tail
// split into a constant-trip-30 block) so nothing is forced to scratch.
// ---------------------------------------------------------------------------
__global__ __launch_bounds__(256, 2) void k_edge(
    const float* __restrict__ x,      // [N,5]
    const float* __restrict__ W1,     // [10,64]
    const float* __restrict__ b1,     // [64]
    const float* __restrict__ W2I,    // [32][64][4]
    const float* __restrict__ b2,     // [128]
    const float* __restrict__ WfT,    // [96,256]
    const float* __restrict__ nn1b,   // [94]
    const float* __restrict__ nn2WT,  // [64,94]
    const float* __restrict__ nn2b,   // [64]
    float* __restrict__ pmax,         // [4096,64]
    float* __restrict__ pmin,
    float* __restrict__ psum)
{
    __shared__ float pool[10240];     // 40960 B -> 4 blocks/CU
    float* XS  = pool;                      // [640]   phase 1
    float* KD  = pool + 640;                // [1024]  phase 1
    int*   KI  = (int*)(pool + 1664);       // [1024]  phase 1
    int*   NBR = (int*)(pool + 2688);       // [256]   phase 1
    float* AGM = pool;                      // [4352]  phase 2 (64x68)
    float* AGS = pool + 4352;               // [4352]  phase 2
    float* NNH = pool;                      // [6016]  phase 3 (94x64 ch-major)
    float* HT  = pool + 6016;               // [4224]  phase 3 (64x66)

    const int t = threadIdx.x;
    const int lane = t & 63;
    // wave id in an SGPR so weight addresses are provably wave-uniform (s_load)
    const int w = __builtin_amdgcn_readfirstlane(t >> 6);
    const int graph = blockIdx.x >> 1;
    const int node0 = (blockIdx.x & 1) * 64;

    for (int i = t; i < NPER * 5; i += 256) XS[i] = x[(size_t)graph * (NPER * 5) + i];
    __syncthreads();

    // ---- KNN: 4 threads per node (q = t>>6), branchless insert, LDS merge
    {
        const int nl2 = t & 63;
        const int q  = t >> 6;
        const int ng2 = node0 + nl2;
        const float px = XS[ng2 * 5 + 0], py = XS[ng2 * 5 + 1], pz = XS[ng2 * 5 + 2];
        float bd[4] = {3e38f, 3e38f, 3e38f, 3e38f};
        int   bi[4] = {0, 0, 0, 0};
        const int m0 = q * 32;
        for (int m = m0; m < m0 + 32; ++m) {
            float dx = XS[m * 5 + 0] - px, dy = XS[m * 5 + 1] - py, dz = XS[m * 5 + 2] - pz;
            float d2 = __fadd_rn(__fadd_rn(__fmul_rn(dx, dx), __fmul_rn(dy, dy)),
                                 __fmul_rn(dz, dz));
            d2 = (m == ng2) ? 3.0e38f : d2;   // self never inserted (strict <)
            ins4(d2, m, bd, bi);
        }
        #pragma unroll
        for (int s = 0; s < 4; ++s) { KD[(q * 4 + s) * 64 + nl2] = bd[s]; KI[(q * 4 + s) * 64 + nl2] = bi[s]; }
    }
    __syncthreads();
    if (t < 64) {                           // merge quarters in global index order
        float bd[4] = {3e38f, 3e38f, 3e38f, 3e38f};
        int   bi[4] = {0, 0, 0, 0};
        #pragma unroll
        for (int q = 0; q < 4; ++q)
            #pragma unroll
            for (int s = 0; s < 4; ++s)
                ins4(KD[(q * 4 + s) * 64 + t], KI[(q * 4 + s) * 64 + t], bd, bi);
        #pragma unroll
        for (int s = 0; s < 4; ++s) NBR[t * 4 + s] = bi[s];
    }
    __syncthreads();

    // ---- MLP1: lane-per-edge, h1[64] in registers (W1/b1 uniform -> s_load)
    const int nl = t >> 2;
    const int kk = t & 3;
    const int n_g = node0 + nl;
    const int j   = NBR[nl * 4 + kk];
    float f[10];
    #pragma unroll
    for (int d = 0; d < 5; ++d) { f[d] = XS[n_g * 5 + d]; f[5 + d] = XS[j * 5 + d] - f[d]; }
    float h1v[64];
    #pragma unroll
    for (int c = 0; c < 64; ++c) h1v[c] = b1[c];
    #pragma unroll
    for (int d = 0; d < 10; ++d) {
        float fd = f[d];
        #pragma unroll
        for (int c = 0; c < 64; ++c) h1v[c] = fmaf(fd, W1[d * 64 + c], h1v[c]);
    }
    #pragma unroll
    for (int c = 0; c < 64; ++c) h1v[c] = fmaxf(h1v[c], 0.0f);
    __syncthreads();   // XS/NBR dead; AGM/AGS may alias them now

    // ---- nn1 accumulators (wave owns 24 jj channels, node = lane)
    float acc[24];
    const int jj0 = __builtin_amdgcn_readfirstlane(w * 24);
    #pragma unroll
    for (int i = 0; i < 24; ++i) acc[i] = (jj0 + i < 94) ? nn1b[jj0 + i] : 0.0f;

    for (int h = 0; h < 2; ++h) {
        // MLP2: 16 groups of 4 channels -> 4 independent FMA chains
        for (int ch = 0; ch < 64; ch += 4) {
            const float* wp = W2I + (size_t)(h * 16 + (ch >> 2)) * 256;  // uniform
            float m0 = b2[h * 64 + ch], m1 = b2[h * 64 + ch + 1];
            float m2 = b2[h * 64 + ch + 2], m3 = b2[h * 64 + ch + 3];
            #pragma unroll
            for (int c = 0; c < 64; ++c) {
                float hv = h1v[c];
                m0 = fmaf(hv, wp[c * 4 + 0], m0);
                m1 = fmaf(hv, wp[c * 4 + 1], m1);
                m2 = fmaf(hv, wp[c * 4 + 2], m2);
                m3 = fmaf(hv, wp[c * 4 + 3], m3);
            }
            m0 = fmaxf(m0, 0.0f); m1 = fmaxf(m1, 0.0f);
            m2 = fmaxf(m2, 0.0f); m3 = fmaxf(m3, 0.0f);
            float x0 = fmaxf(m0, __shfl_xor(m0, 1));
            float x1 = fmaxf(m1, __shfl_xor(m1, 1));
            float x2 = fmaxf(m2, __shfl_xor(m2, 1));
            float x3 = fmaxf(m3, __shfl_xor(m3, 1));
            x0 = fmaxf(x0, __shfl_xor(x0, 2));
            x1 = fmaxf(x1, __shfl_xor(x1, 2));
            x2 = fmaxf(x2, __shfl_xor(x2, 2));
            x3 = fmaxf(x3, __shfl_xor(x3, 2));
            float s0 = m0 + __shfl_xor(m0, 1);
            float s1 = m1 + __shfl_xor(m1, 1);
            float s2 = m2 + __shfl_xor(m2, 1);
            float s3 = m3 + __shfl_xor(m3, 1);
            s0 += __shfl_xor(s0, 2);
            s1 += __shfl_xor(s1, 2);
            s2 += __shfl_xor(s2, 2);
            s3 += __shfl_xor(s3, 2);
            if (kk == 0) {
                *(float4*)&AGM[nl * 68 + ch] = make_float4(x0, x1, x2, x3);
                *(float4*)&AGS[nl * 68 + ch] = make_float4(s0, s1, s2, s3);
            }
        }
        __syncthreads();

        // nn1 partial: lane = node; agg rows via b128, chunks of 8; i2 fully
        // unrolled so acc[] stays constant-indexed (registers, no scratch)
        for (int cb = 0; cb < 64; cb += 8) {
            float am[8], as_[8];
            #pragma unroll
            for (int i = 0; i < 2; ++i) {
                *(float4*)&am[i * 4]  = *(const float4*)&AGM[lane * 68 + cb + i * 4];
                *(float4*)&as_[i * 4] = *(const float4*)&AGS[lane * 68 + cb + i * 4];
            }
            #pragma unroll
            for (int i2 = 0; i2 < 24; ++i2) {
                const float* wa = WfT + (size_t)(jj0 + i2) * 256 + h * 64 + cb;
                const float* wb = wa + 128;
                float a = acc[i2];
                #pragma unroll
                for (int i = 0; i < 8; ++i) a = fmaf(am[i], wa[i], fmaf(as_[i], wb[i], a));
                acc[i2] = a;
            }
        }
        __syncthreads();   // before next half overwrites agg / NNH alias
    }

    // ---- nnh = relu(nn1), channel-major [jj][node] (conflict-free stride 64)
    #pragma unroll
    for (int i2 = 0; i2 < 24; ++i2)
        if (jj0 + i2 < 94) NNH[(jj0 + i2) * 64 + lane] = fmaxf(acc[i2], 0.0f);
    __syncthreads();

    // ---- nn2: lane = node, wave owns 16 output channels (weights s_load).
    // Constant trip counts (32,32,30) so hv[] is register-allocated.
    {
        const int ch0 = __builtin_amdgcn_readfirstlane(w * 16);
        float acc2[16];
        #pragma unroll
        for (int i = 0; i < 16; ++i) acc2[i] = nn2b[ch0 + i];
        #pragma unroll 1
        for (int cb = 0; cb < 64; cb += 32) {
            float hv[32];
            #pragma unroll
            for (int i = 0; i < 32; ++i) hv[i] = NNH[(cb + i) * 64 + lane];
            #pragma unroll
            for (int i = 0; i < 16; ++i) {
                const float* wp = nn2WT + (size_t)(ch0 + i) * 94 + cb;
                float a = acc2[i];
                #pragma unroll
                for (int c = 0; c < 32; ++c) a = fmaf(hv[c], wp[c], a);
                acc2[i] = a;
            }
        }
        {   // tail c = 64..93 (constant trip 30)
            float hv[30];
            #pragma unroll
            for (int i = 0; i < 30; ++i) hv[i] = NNH[(64 + i) * 64 + lane];
            #pragma unroll
            for (int i = 0; i < 16; ++i) {
                const float* wp = nn2WT + (size_t)(ch0 + i) * 94 + 64;
                float a = acc2[i];
                #pragma unroll
                for (int c = 0; c < 30; ++c) a = fmaf(hv[c], wp[c], a);
                acc2[i] = a;
            }
        }
        #pragma unroll
        for (int i = 0; i < 8; ++i)
            *(float2*)&HT[lane * 66 + ch0 + i * 2] =
                make_float2(acc2[i * 2], acc2[i * 2 + 1]);
    }
    __syncthreads();

    // ---- partial pooling over this block's 64 nodes
    if (t < 64) {
        float mx = -3e38f, mn = 3e38f, sm = 0.0f;
        for (int n = 0; n < 64; ++n) {
            float v = HT[n * 66 + t];
            mx = fmaxf(mx, v); mn = fminf(mn, v); sm += v;
        }
        pmax[(size_t)blockIdx.x * 64 + t] = mx;
        pmin[(size_t)blockIdx.x * 64 + t] = mn;
        psum[(size_t)blockIdx.x * 64 + t] = sm;
    }
}

// ---------------------------------------------------------------------------
__global__ void k_pool(const float* __restrict__ pmax, const float* __restrict__ pmin,
                       const float* __restrict__ psum, float* __restrict__ g_out)
{
    const int t = threadIdx.x;
    const int g = blockIdx.x * 4 + (t >> 6);
    const int ch = t & 63;
    const size_t a = (size_t)(2 * g) * 64 + ch, b = a + 64;
    float mx = fmaxf(pmax[a], pmax[b]);
    float mn = fminf(pmin[a], pmin[b]);
    float sm = psum[a] + psum[b];
    float* gp = g_out + (size_t)g * 256;
    gp[ch]        = fmaxf(mx, 0.0f);
    gp[64 + ch]   = fmaxf(mn, 0.0f);
    gp[128 + ch]  = fmaxf(sm, 0.0f);
    gp[192 + ch]  = fmaxf(sm * (1.0f / 128.0f), 0.0f);
}

// ---------------------------------------------------------------------------
__global__ __launch_bounds__(128) void k_gru(
    const float* __restrict__ g, const float* __restrict__ h1_in,
    const float* __restrict__ wih0, const float* __restrict__ whh0,
    const float* __restrict__ bih0, const float* __restrict__ bhh0,
    const float* __restrict__ wih1, const float* __restrict__ whh1,
    const float* __restrict__ bih1, const float* __restrict__ bhh1,
    float* __restrict__ out1, float* __restrict__ hT)
{
    __shared__ float xt[4][256];
    __shared__ float h0[4][32];
    __shared__ float h1l[4][32];
    const int tid = threadIdx.x;
    const int e = tid >> 5;
    const int j = tid & 31;
    const int b = blockIdx.x * 4 + e;

    h0[e][j]  = h1_in[b * 32 + j];
    h1l[e][j] = h1_in[32768 + b * 32 + j];
    __syncthreads();

    for (int t = 0; t < 2; ++t) {
        for (int c = j; c < 256; c += 32)
            xt[e][c] = g[(size_t)(t * 1024 + 4 * c + (b >> 8)) * 256 + (b & 255)];
        __syncthreads();

        float gi0 = bih0[j], gi1 = bih0[32 + j], gi2 = bih0[64 + j];
        for (int c = 0; c < 256; ++c) {
            float xv = xt[e][c];
            gi0 += xv * wih0[j * 256 + c];
            gi1 += xv * wih0[(32 + j) * 256 + c];
            gi2 += xv * wih0[(64 + j) * 256 + c];
        }
        float gh0 = bhh0[j], gh1 = bhh0[32 + j], gh2 = bhh0[64 + j];
        #pragma unroll
        for (int c = 0; c < 32; ++c) {
            float hv = h0[e][c];
            gh0 += hv * whh0[j * 32 + c];
            gh1 += hv * whh0[(32 + j) * 32 + c];
            gh2 += hv * whh0[(64 + j) * 32 + c];
        }
        float r = 1.0f / (1.0f + expf(-(gi0 + gh0)));
        float z = 1.0f / (1.0f + expf(-(gi1 + gh1)));
        float nn = tanhf(gi2 + r * gh2);
        float hn0 = (1.0f - z) * nn + z * h0[e][j];
        __syncthreads();
        h0[e][j] = hn0;
        __syncthreads();

        float ai0 = bih1[j], ai1 = bih1[32 + j], ai2 = bih1[64 + j];
        #pragma unroll
        for (int c = 0; c < 32; ++c) {
            float xv = h0[e][c];
            ai0 += xv * wih1[j * 32 + c];
            ai1 += xv * wih1[(32 + j) * 32 + c];
            ai2 += xv * wih1[(64 + j) * 32 + c];
        }
        float ah0 = bhh1[j], ah1 = bhh1[32 + j], ah2 = bhh1[64 + j];
        #pragma unroll
        for (int c = 0; c < 32; ++c) {
            float hv = h1l[e][c];
            ah0 += hv * whh1[j * 32 + c];
            ah1 += hv * whh1[(32 + j) * 32 + c];
            ah2 += hv * whh1[(64 + j) * 32 + c];
        }
        float r1 = 1.0f / (1.0f + expf(-(ai0 + ah0)));
        float z1 = 1.0f / (1.0f + expf(-(ai1 + ah1)));
        float n1 = tanhf(ai2 + r1 * ah2);
        float hn1 = (1.0f - z1) * n1 + z1 * h1l[e][j];
        __syncthreads();
        h1l[e][j] = hn1;
        out1[(size_t)(t * 1024 + b) * 32 + j] = hn1;
        __syncthreads();
    }
    hT[b * 32 + j]         = h0[e][j];
    hT[32768 + b * 32 + j] = h1l[e][j];
}

__global__ void k_final(const float* __restrict__ out1,
                        const float* __restrict__ nn4W, const float* __restrict__ nn4b,
                        float* __restrict__ y)
{
    const int r = blockIdx.x * 256 + threadIdx.x;
    if (r >= 2048) return;
    const int t = r >> 10, rp = r & 1023;
    const int f = rp >> 5, bb0 = (rp & 31) << 5;
    float acc = nn4b[0];
    #pragma unroll
    for (int c = 0; c < 32; ++c)
        acc += fmaxf(out1[(size_t)(t * 1024 + bb0 + c) * 32 + f], 0.0f) * nn4W[c];
    y[r] = fmaxf(acc, 0.0f);
}

extern "C" void kernel_launch(void* const* d_in, const int* in_sizes, int n_in,
                              void* d_out, int out_size, void* d_ws, size_t ws_size,
                              hipStream_t stream) {
    const float* x    = (const float*)d_in[0];
    const float* h1i  = (const float*)d_in[2];
    const float* W1   = (const float*)d_in[3];
    const float* b1   = (const float*)d_in[4];
    const float* W2   = (const float*)d_in[5];
    const float* b2   = (const float*)d_in[6];
    const float* nn1W = (const float*)d_in[7];
    const float* nn1b = (const float*)d_in[8];
    const float* nn2W = (const float*)d_in[9];
    const float* nn2b = (const float*)d_in[10];
    const float* nn4W = (const float*)d_in[11];
    const float* nn4b = (const float*)d_in[12];
    const float* wih0 = (const float*)d_in[13];
    const float* whh0 = (const float*)d_in[14];
    const float* bih0 = (const float*)d_in[15];
    const float* bhh0 = (const float*)d_in[16];
    const float* wih1 = (const float*)d_in[17];
    const float* whh1 = (const float*)d_in[18];
    const float* bih1 = (const float*)d_in[19];
    const float* bhh1 = (const float*)d_in[20];

    float* ws = (float*)d_ws;
    float* g_buf  = ws;                   // 524288
    float* out1   = g_buf + 524288;       // 65536
    float* W2I    = out1 + 65536;         // 8192
    float* nn2WT  = W2I + 8192;           // 6016
    float* WfT    = nn2WT + 6016;         // 24576 (96x256)
    float* pmax   = WfT + 24576;          // 262144
    float* pmin   = pmax + 262144;        // 262144
    float* psum   = pmin + 262144;        // 262144

    float* y  = (float*)d_out;            // [2048]
    float* hT = y + 2048;                 // [2,1024,32]

    hipLaunchKernelGGL(k_prep, dim3(152), dim3(256), 0, stream,
                       W2, nn2W, nn1W, W2I, nn2WT, WfT);
    hipLaunchKernelGGL(k_edge, dim3(4096), dim3(256), 0, stream,
                       x, W1, b1, W2I, b2, WfT, nn1b, nn2WT, nn2b,
                       pmax, pmin, psum);
    hipLaunchKernelGGL(k_pool, dim3(512), dim3(256), 0, stream,
                       pmax, pmin, psum, g_buf);
    hipLaunchKernelGGL(k_gru, dim3(256), dim3(128), 0, stream,
                       g_buf, h1i, wih0, whh0, bih0, bhh0,
                       wih1, whh1, bih1, bhh1, out1, hT);
    hipLaunchKernelGGL(k_final, dim3(8), dim3(256), 0, stream,
                       out1, nn4W, nn4b, y);
}